// Round 7
// baseline (299.246 us; speedup 1.0000x reference)
//
#include <hip/hip_runtime.h>

typedef unsigned short u16;
typedef __bf16 bf16x8 __attribute__((ext_vector_type(8)));
typedef float f32x4 __attribute__((ext_vector_type(4)));

__device__ __forceinline__ float b2f(u16 x) {
    union { float f; unsigned u; } v; v.u = ((unsigned)x) << 16; return v.f;
}
__device__ __forceinline__ u16 f2b(float f) {
    union { float f; unsigned u; } v; v.f = f;
    unsigned u = v.u;
    return (u16)((u + 0x7FFFu + ((u >> 16) & 1u)) >> 16);
}
// pack two f32 -> two truncated bf16 in one dword (lo=a, hi=b)
__device__ __forceinline__ unsigned pk2(float a, float b) {
    unsigned ua = __float_as_uint(a), ub = __float_as_uint(b);
    return (ub & 0xFFFF0000u) | (ua >> 16);
}
__device__ __forceinline__ f32x4 mfma_16x16x32(bf16x8 a, bf16x8 b, f32x4 c) {
    return __builtin_amdgcn_mfma_f32_16x16x32_bf16(a, b, c, 0, 0, 0);
}
// async global->LDS, 16B per lane. LDS dest = wave-uniform base + lane*16.
__device__ __forceinline__ void gld_lds16(const u16* g, u16* l) {
    __builtin_amdgcn_global_load_lds(
        (const __attribute__((address_space(1))) unsigned int*)g,
        (__attribute__((address_space(3))) unsigned int*)l,
        16, 0, 0);
}

#define VSTRIDE 2080
#define LOG2E 1.44269504f

// ---------------------------------------------------------------------------
// prep: inputs f32->bf16 [0,4096); W_in T+cvt [4096,7168); W_out T+cvt [7168,8192)
// ---------------------------------------------------------------------------
__global__ __launch_bounds__(256) void prep(const float* __restrict__ inputs,
                                            u16* __restrict__ inB,
                                            const float* __restrict__ W_in,
                                            u16* __restrict__ WtB,
                                            const float* __restrict__ W_out,
                                            u16* __restrict__ WotB) {
    __shared__ float T[32][33];
    const int bx = blockIdx.x;
    if (bx < 4096) {
        int i = (bx * 256 + threadIdx.x) * 4;
        float4 v = *(const float4*)(inputs + i);
        ushort4 o;
        o.x = f2b(v.x); o.y = f2b(v.y); o.z = f2b(v.z); o.w = f2b(v.w);
        *(ushort4*)(inB + i) = o;
        return;
    }
    const float* src; u16* dst; int R, C, c0, r0;
    if (bx < 7168) {
        int t = bx - 4096; src = W_in; dst = WtB; R = 1024; C = 3072;
        c0 = (t % 96) * 32; r0 = (t / 96) * 32;
    } else {
        int t = bx - 7168; src = W_out; dst = WotB; R = 1024; C = 1024;
        c0 = (t % 32) * 32; r0 = (t / 32) * 32;
    }
    int tr = threadIdx.x >> 5, tc = threadIdx.x & 31;
#pragma unroll
    for (int p = 0; p < 4; ++p)
        T[tr + p * 8][tc] = src[(size_t)(r0 + tr + p * 8) * C + c0 + tc];
    __syncthreads();
#pragma unroll
    for (int p = 0; p < 4; ++p)
        dst[(size_t)(c0 + tr + p * 8) * R + r0 + tc] = f2b(T[tc][tr + p * 8]);
}

// ---------------------------------------------------------------------------
// GEMM (m97 structure): C[M,N] = A[M,K] * Bt[N,K]^T. bf16 in, f32 accum.
// ---------------------------------------------------------------------------
template <bool F32OUT>
__global__ __launch_bounds__(256) void gemm_tn(const u16* __restrict__ A,
                                               const u16* __restrict__ Bt,
                                               void* __restrict__ Cv,
                                               int M, int N, int K) {
    __shared__ u16 As[128 * 32];
    __shared__ u16 Bs[128 * 32];
    const int tid = threadIdx.x;
    const int m0 = blockIdx.y * 128;
    const int n0 = blockIdx.x * 128;
    const int w = tid >> 6, lane = tid & 63;
    const int col16 = lane & 15, quad = lane >> 4;
    const int wm = (w >> 1) * 64, wn = (w & 1) * 64;
    const int srow = (lane >> 2), sseg = (lane & 3) * 8;

    f32x4 acc[4][4];
#pragma unroll
    for (int i = 0; i < 4; ++i)
#pragma unroll
        for (int j = 0; j < 4; ++j) acc[i][j] = (f32x4){0.f, 0.f, 0.f, 0.f};

    for (int kt = 0; kt < K; kt += 32) {
#pragma unroll
        for (int cc = 0; cc < 2; ++cc) {
            int c = w * 2 + cc;
            int row = c * 16 + srow;
            gld_lds16(A + (size_t)(m0 + row) * K + kt + sseg, &As[c * 512 + lane * 8]);
            gld_lds16(Bt + (size_t)(n0 + row) * K + kt + sseg, &Bs[c * 512 + lane * 8]);
        }
        __syncthreads();

        bf16x8 af[4], bfr[4];
#pragma unroll
        for (int i = 0; i < 4; ++i)
            af[i] = *(const bf16x8*)&As[(wm + i * 16 + col16) * 32 + quad * 8];
#pragma unroll
        for (int j = 0; j < 4; ++j)
            bfr[j] = *(const bf16x8*)&Bs[(wn + j * 16 + col16) * 32 + quad * 8];
#pragma unroll
        for (int i = 0; i < 4; ++i)
#pragma unroll
            for (int j = 0; j < 4; ++j)
                acc[i][j] = mfma_16x16x32(af[i], bfr[j], acc[i][j]);
        __syncthreads();
    }

#pragma unroll
    for (int i = 0; i < 4; ++i) {
#pragma unroll
        for (int r = 0; r < 4; ++r) {
            int m = m0 + wm + i * 16 + quad * 4 + r;
            if (F32OUT) {
                float* Crow = (float*)Cv + (size_t)m * N + n0 + wn;
#pragma unroll
                for (int j = 0; j < 4; ++j)
                    Crow[j * 16 + col16] = acc[i][j][r];
            } else {
                u16* Crow = (u16*)Cv + (size_t)m * N + n0 + wn;
#pragma unroll
                for (int j = 0; j < 4; ++j)
                    Crow[j * 16 + col16] = f2b(acc[i][j][r]);
            }
        }
    }
}

// ---------------------------------------------------------------------------
// Fused rope + v_transpose. blocks [0,1024): RoPE (q scaled log2e/8);
// blocks [1024,3072): V transpose into Vt [BH][64][VSTRIDE].
// ---------------------------------------------------------------------------
__global__ __launch_bounds__(256) void rope_vt(const u16* __restrict__ qkv,
                                               const int* __restrict__ segpos,
                                               u16* __restrict__ Qh,
                                               u16* __restrict__ Kh,
                                               u16* __restrict__ Vt) {
    __shared__ u16 T[32][72];
    const int bx = blockIdx.x;
    if (bx < 1024) {
        int t = bx * 256 + threadIdx.x;
        int seg = t & 3;
        int h = (t >> 2) & 15;
        int row = t >> 6;
        float pos = (float)segpos[row];
        const u16* base = qkv + (size_t)row * 3072 + h * 192 + seg * 8;
        union { uint4 u; u16 s[8]; } q1, q2, k1, k2, oq1, oq2, ok1, ok2;
        q1.u = *(const uint4*)(base);
        q2.u = *(const uint4*)(base + 32);
        k1.u = *(const uint4*)(base + 64);
        k2.u = *(const uint4*)(base + 96);
        const float qs = 0.125f * LOG2E;
#pragma unroll
        for (int j = 0; j < 8; ++j) {
            int d = seg * 8 + j;
            float inv_freq = __expf(-(float)d * (9.210340371976184f / 32.0f));
            float ang = pos * inv_freq;
            float c = __cosf(ang), s = __sinf(ang);
            float a1 = b2f(q1.s[j]), a2 = b2f(q2.s[j]);
            float b1 = b2f(k1.s[j]), b2v = b2f(k2.s[j]);
            oq1.s[j] = f2b((a1 * c - a2 * s) * qs);
            oq2.s[j] = f2b((a1 * s + a2 * c) * qs);
            ok1.s[j] = f2b(b1 * c - b2v * s);
            ok2.s[j] = f2b(b1 * s + b2v * c);
        }
        int b = row >> 11, srow = row & 2047;
        size_t idx = ((size_t)(b * 16 + h) * 2048 + srow) * 64 + seg * 8;
        *(uint4*)&Qh[idx]      = oq1.u;
        *(uint4*)&Qh[idx + 32] = oq2.u;
        *(uint4*)&Kh[idx]      = ok1.u;
        *(uint4*)&Kh[idx + 32] = ok2.u;
        return;
    }
    int bxx = bx - 1024;
    int s0 = (bxx & 63) * 32;
    int bh = bxx >> 6;
    int b = bh >> 4, h = bh & 15;
    int t = threadIdx.x;
    {
        int r = t >> 3, seg = t & 7;
        const u16* src = qkv + (size_t)(b * 2048 + s0 + r) * 3072 + h * 192 + 128 + seg * 8;
        *(uint4*)&T[r][seg * 8] = *(const uint4*)src;
    }
    __syncthreads();
    {
        int d = t >> 2, ss = (t & 3) * 8;
        union { uint4 u; u16 s[8]; } w;
#pragma unroll
        for (int j = 0; j < 8; ++j) w.s[j] = T[ss + j][d];
        *(uint4*)(Vt + (size_t)bh * 64 * VSTRIDE + (size_t)d * VSTRIDE + s0 + ss) = w.u;
    }
}

// ---------------------------------------------------------------------------
// Flash attention v14: persistent workers + PER-XCD work queues.
//  - v13's global queue destroyed bh<->XCD L2 affinity (FETCH 12.4->64.5MB,
//    staging L2-hit -> HBM-miss). v14: 8 queues, one per XCD; each block reads
//    its physical XCD via s_getreg(HW_REG_XCC_ID) and pops units of that
//    XCD's 4 bh only (34 units/bh x 4 = 136/queue, heaviest-first = greedy
//    LPT). If its queue drains, it steals from the next XCD (correct: each
//    (queue,ticket) claimed exactly once; slot mapping is unit-determined).
//  - 768 blocks (3/CU residency: ~49.7KB LDS, VGPR<=96).
//  - Chunk body is v9's verbatim (2-phase gld_lds pipeline, vmcnt(4), XOR
//    swizzle, fixed-max base-2 softmax, packed P writes).
// ---------------------------------------------------------------------------
#define FIXED_M2 34.6246561f    // 24 * log2(e)
#define UNITS_PER_Q 136

// per-bh unit tables (34 entries), ordered by descending chunk count (LPT).
__device__ const int UTQ[34] = {14,14,14,13, 9, 9, 4,
                                13,13,12,12, 8, 8,
                                15,15,15,15,12,11,11,11,10, 7, 7, 3,
                                10,10, 6, 6,  5, 5, 2,  1,  0};
__device__ const int UC0[34] = { 0,10,20, 0, 0,10, 0,
                                10,19, 0, 9, 0, 9,
                                 0, 8,16,24,18, 0, 8,16, 0, 0, 8, 0,
                                 8,15, 0, 7,  0, 6, 0,  0,  0};
__device__ const int UNC[34] = {10,10,10,10,10,10,10,
                                 9, 9, 9, 9, 9, 9,
                                 8, 8, 8, 8, 8, 8, 8, 8, 8, 8, 8, 8,
                                 7, 7, 7, 7,  6, 6, 6,  4,  2};
__device__ const int UPS[34] = { 0, 1, 2, 3, 4, 5,-1,
                                 6, 7, 8, 9,10,11,
                                12,13,14,15,16,17,18,19,20,21,22,-1,
                                23,24,25,26, 27,28,-1, -1, -1};
// reduce tables: 11 multi-unit tiles (tq 5..15); ps lists per tile
__device__ const int RTQ[11]    = {15,14,13,12,11,10,9,8,7,6,5};
__device__ const int RN[11]     = {4,3,3,3,3,3,2,2,2,2,2};
__device__ const int RUS[11][4] = {{12,13,14,15},{0,1,2,-1},{3,6,7,-1},{8,9,16,-1},
                                   {17,18,19,-1},{20,23,24,-1},{4,5,-1,-1},{10,11,-1,-1},
                                   {21,22,-1,-1},{25,26,-1,-1},{27,28,-1,-1}};

__global__ __launch_bounds__(256) void attn_v14(const u16* __restrict__ Qh,
                                                const u16* __restrict__ Kh,
                                                const u16* __restrict__ Vt,
                                                u16* __restrict__ X,
                                                float* __restrict__ Opart,
                                                float* __restrict__ Lpart,
                                                unsigned* __restrict__ cnt) {
    __shared__ u16 Ks[2][64 * 64];   // [buf][k-row][64 d]  (8KB/buf)
    __shared__ u16 Vs[2][64 * 64];   // [buf][d-row][64 k]  (8KB/buf)
    __shared__ u16 Ps[4][32 * 64];   // wave-private P [32 q][64 k], swizzled
    __shared__ float lred[4][32];
    __shared__ int enc_s;
    const int tid = threadIdx.x;
    const int w = tid >> 6, lane = tid & 63;
    const int col16 = lane & 15, quad = lane >> 4;
    const int swz = (col16 & 7) << 3;      // row-XOR for all LDS tiles (u16 units)
    // staging decomposition: each gld_lds covers 8 rows x 128B; lane = r*8+s.
    const int sr = lane >> 3;              // row within instr (0..7)
    const int sg = ((lane & 7) ^ sr) * 8;  // pre-swizzled 16B granule (u16 units)
    u16* Pw = Ps[w];

    // physical XCD of this block (wave-uniform SGPR)
    unsigned xcc;
    asm volatile("s_getreg_b32 %0, hwreg(HW_REG_XCC_ID)" : "=s"(xcc));
    int qoff = 0;                          // tid0's persistent queue cursor

    for (;;) {
        // ---- pop next unit: own XCD's queue first, then steal ----
        __syncthreads();                   // prior unit's LDS reads + enc_s reads done
        if (tid == 0) {
            int enc = -1;
            while (qoff < 8) {
                int qi = ((int)xcc + qoff) & 7;
                unsigned v = atomicAdd(&cnt[qi], 1u);
                if (v < UNITS_PER_Q) { enc = (qi << 8) | (int)v; break; }
                ++qoff;
            }
            enc_s = enc;
        }
        __syncthreads();                   // enc_s visible; also drains vmcnt/lgkm
        const int enc = enc_s;
        if (enc < 0) return;
        const int qi = enc >> 8, uu = enc & 255;
        const int bh = qi * 4 + (uu & 3);
        const int idx = uu >> 2;
        const int tq = UTQ[idx];
        const int c0 = UC0[idx];
        const int nc = UNC[idx];
        const int ps = UPS[idx];
        const int q0 = tq * 128 + w * 32;
        const u16* Qp = Qh + (size_t)bh * 2048 * 64;
        const u16* Kp = Kh + (size_t)bh * 2048 * 64;
        const u16* Vp = Vt + (size_t)bh * 64 * VSTRIDE;

        // Q fragments (used as B-operand of K*Q^T -- identical lane data)
        bf16x8 qa[2][2];
#pragma unroll
        for (int t = 0; t < 2; ++t)
#pragma unroll
            for (int hf = 0; hf < 2; ++hf)
                qa[t][hf] = *(const bf16x8*)&Qp[(size_t)(q0 + t * 16 + col16) * 64 + hf * 32 + quad * 8];

        float l_acc[2] = {0.f, 0.f};
        f32x4 o[2][4];
#pragma unroll
        for (int t = 0; t < 2; ++t)
#pragma unroll
            for (int f = 0; f < 4; ++f) o[t][f] = (f32x4){0.f, 0.f, 0.f, 0.f};

        // ---- prologue: stage chunk c0 into buf 0 (4 instrs/wave: 2 K + 2 V) ----
        {
            const int k0 = c0 * 64;
#pragma unroll
            for (int i = 0; i < 2; ++i) {
                int c = w * 2 + i;
                gld_lds16(Kp + (size_t)(k0 + c * 8 + sr) * 64 + sg, &Ks[0][c * 512 + lane * 8]);
            }
#pragma unroll
            for (int i = 0; i < 2; ++i) {
                int c = w * 2 + i;
                gld_lds16(Vp + (size_t)(c * 8 + sr) * VSTRIDE + k0 + sg, &Vs[0][c * 512 + lane * 8]);
            }
        }

        for (int ci = 0; ci < nc; ++ci) {
            const int cur = ci & 1;
            const u16* KsC = Ks[cur];
            const u16* VsC = Vs[cur];

            // ---- issue next chunk's stage into the other buffer ----
            if (ci + 1 < nc) {
                const int k0n = (c0 + ci + 1) * 64;
                u16* Kd = Ks[cur ^ 1];
                u16* Vd = Vs[cur ^ 1];
#pragma unroll
                for (int i = 0; i < 2; ++i) {
                    int c = w * 2 + i;
                    gld_lds16(Kp + (size_t)(k0n + c * 8 + sr) * 64 + sg, Kd + c * 512 + lane * 8);
                }
#pragma unroll
                for (int i = 0; i < 2; ++i) {
                    int c = w * 2 + i;
                    gld_lds16(Vp + (size_t)(c * 8 + sr) * VSTRIDE + k0n + sg, Vd + c * 512 + lane * 8);
                }
                // wait only for CURRENT chunk's 4 loads; next chunk's 4 stay in flight
                asm volatile("s_waitcnt vmcnt(4)" ::: "memory");
            } else {
                asm volatile("s_waitcnt vmcnt(0)" ::: "memory");
            }
            asm volatile("s_barrier" ::: "memory");

            const int k0 = (c0 + ci) * 64;

            // ---- K*Q^T -> S^T ----
            f32x4 s[2][4];
#pragma unroll
            for (int t = 0; t < 2; ++t)
#pragma unroll
                for (int kt = 0; kt < 4; ++kt) s[t][kt] = (f32x4){0.f, 0.f, 0.f, 0.f};
#pragma unroll
            for (int kt = 0; kt < 4; ++kt) {
                const u16* kb = &KsC[(kt * 16 + col16) * 64];
                bf16x8 kf0 = *(const bf16x8*)&kb[(quad * 8) ^ swz];
                bf16x8 kf1 = *(const bf16x8*)&kb[(32 + quad * 8) ^ swz];
                s[0][kt] = mfma_16x16x32(kf0, qa[0][0], s[0][kt]);
                s[0][kt] = mfma_16x16x32(kf1, qa[0][1], s[0][kt]);
                s[1][kt] = mfma_16x16x32(kf0, qa[1][0], s[1][kt]);
                s[1][kt] = mfma_16x16x32(kf1, qa[1][1], s[1][kt]);
            }

            // ---- softmax: p = 2^(s - M2), per-lane l, packed dword P writes ----
            const bool domask = (k0 + 63 > q0);
#pragma unroll
            for (int t = 0; t < 2; ++t) {
                const int qg = q0 + t * 16 + col16;
                float rs = 0.f;
#pragma unroll
                for (int kt = 0; kt < 4; ++kt) {
                    float p[4];
#pragma unroll
                    for (int r = 0; r < 4; ++r) {
                        float sv = s[t][kt][r];
                        if (domask && (k0 + kt * 16 + quad * 4 + r > qg)) sv = -1e30f;
                        p[r] = __builtin_amdgcn_exp2f(sv - FIXED_M2);
                        rs += p[r];
                    }
                    unsigned* prow = (unsigned*)&Pw[(t * 16 + col16) * 64 + ((kt * 16 + quad * 4) ^ swz)];
                    prow[0] = pk2(p[0], p[1]);
                    prow[1] = pk2(p[2], p[3]);
                }
                l_acc[t] += rs;
            }
            asm volatile("s_waitcnt lgkmcnt(0)" ::: "memory");  // P writes -> reads

            // ---- PV: 16 MFMAs ----
#pragma unroll
            for (int ss = 0; ss < 2; ++ss) {
                const int ko = (ss * 32 + quad * 8) ^ swz;
                bf16x8 pf0 = *(const bf16x8*)&Pw[(col16) * 64 + ko];
                bf16x8 pf1 = *(const bf16x8*)&Pw[(16 + col16) * 64 + ko];
#pragma unroll
                for (int f = 0; f < 4; ++f) {
                    bf16x8 vf = *(const bf16x8*)&VsC[(f * 16 + col16) * 64 + ko];
                    o[0][f] = mfma_16x16x32(pf0, vf, o[0][f]);
                    o[1][f] = mfma_16x16x32(pf1, vf, o[1][f]);
                }
            }
            // all LDS reads of buf[cur] complete before next iteration's stage
            asm volatile("s_waitcnt lgkmcnt(0)" ::: "memory");
            asm volatile("s_barrier" ::: "memory");
        }

        // ---- l reduction across quads (butterfly -> every lane has row total) ----
        float lt[2];
#pragma unroll
        for (int t = 0; t < 2; ++t) {
            float l = l_acc[t];
            l += __shfl_xor(l, 16);
            l += __shfl_xor(l, 32);
            lt[t] = l;
            if (quad == 0) lred[w][t * 16 + col16] = l;
        }
        asm volatile("s_waitcnt lgkmcnt(0)" ::: "memory");

        if (ps >= 0) {
            // ---- partial epilogue: raw O (no divide) + l to workspace ----
            const int pg = bh * 29 + ps;
            float* Op = Opart + ((size_t)pg * 128 + w * 32) * 64;
#pragma unroll
            for (int t = 0; t < 2; ++t) {
#pragma unroll
                for (int r = 0; r < 4; ++r) {
                    float* Crow = Op + (t * 16 + quad * 4 + r) * 64;
#pragma unroll
                    for (int f = 0; f < 4; ++f)
                        Crow[f * 16 + col16] = o[t][f][r];
                }
            }
            if (quad == 0) {
                float* Lp = Lpart + (size_t)pg * 128 + w * 32;
#pragma unroll
                for (int t = 0; t < 2; ++t) Lp[t * 16 + col16] = lt[t];
            }
        } else {
            // ---- direct epilogue (single-unit tile): divide and write X ----
            const int b = bh >> 4, h = bh & 15;
#pragma unroll
            for (int t = 0; t < 2; ++t) {
#pragma unroll
                for (int r = 0; r < 4; ++r) {
                    float inv = 1.0f / lred[w][t * 16 + quad * 4 + r];
                    int srow = q0 + t * 16 + quad * 4 + r;
                    u16* Xp = X + ((size_t)(b * 2048 + srow)) * 1024 + h * 64;
#pragma unroll
                    for (int f = 0; f < 4; ++f)
                        Xp[f * 16 + col16] = f2b(o[t][f][r] * inv);
                }
            }
        }
        // next pop's __syncthreads drains stores and fences LDS reuse
    }
}

// ---------------------------------------------------------------------------
// attn_reduce: combine 2-4 partials per (bh, tq in 5..15): X = (sum O)/(sum l)
// ---------------------------------------------------------------------------
__global__ __launch_bounds__(256) void attn_reduce(const float* __restrict__ Opart,
                                                   const float* __restrict__ Lpart,
                                                   u16* __restrict__ X) {
    const int bh = blockIdx.x;           // 0..31
    const int ti = blockIdx.y;           // 0..10
    const int tq = RTQ[ti];
    const int np = RN[ti];
    const int tid = threadIdx.x;
    const int b = bh >> 4, h = bh & 15;
#pragma unroll
    for (int i = 0; i < 8; ++i) {
        int e4 = i * 256 + tid;          // float4 index within 128x64 tile
        int q = e4 >> 4, d0 = (e4 & 15) * 4;
        float4 a = {0.f, 0.f, 0.f, 0.f};
        float l = 0.f;
        for (int uu = 0; uu < np; ++uu) {
            const size_t g = (size_t)(bh * 29 + RUS[ti][uu]);
            float4 c = ((const float4*)Opart)[g * 2048 + e4];
            a.x += c.x; a.y += c.y; a.z += c.z; a.w += c.w;
            l += Lpart[g * 128 + q];
        }
        float inv = 1.0f / l;
        ushort4 ov;
        ov.x = f2b(a.x * inv); ov.y = f2b(a.y * inv);
        ov.z = f2b(a.z * inv); ov.w = f2b(a.w * inv);
        *(ushort4*)&X[((size_t)(b * 2048 + tq * 128 + q)) * 1024 + h * 64 + d0] = ov;
    }
}

// ---------------------------------------------------------------------------
// launch
// ---------------------------------------------------------------------------
extern "C" void kernel_launch(void* const* d_in, const int* in_sizes, int n_in,
                              void* d_out, int out_size, void* d_ws, size_t ws_size,
                              hipStream_t stream) {
    const float* inputs = (const float*)d_in[0];
    const int* segpos   = (const int*)d_in[1];
    const float* W_in   = (const float*)d_in[3];
    const float* W_out  = (const float*)d_in[4];
    float* out = (float*)d_out;

    u16* ws = (u16*)d_ws;
    u16* qkv   = ws;                               // 4096*3072 bf16
    u16* x     = qkv;                              // alias (qkv dead after rope_vt)
    u16* inB   = qkv + 12582912 + 512;
    u16* WtB   = inB + 4194304 + 512;              // W_in^T  [3072][1024]
    u16* WotB  = WtB + 3145728 + 512;              // W_out^T [1024][1024]
    u16* Qh    = WotB + 1048576 + 512;             // [BH][S][64]
    u16* Kh    = Qh + 4194304 + 512;
    u16* Vt    = Kh + 4194304 + 512;               // [BH][64][VSTRIDE]
    // split-K partials: region [X_end=4.19M, WtB_end=19.92M) is dead during attn.
    // Opart: 928 slots x 128 x 64 f32 = 15,204,352 u16;
    // Lpart: 928 x 128 f32 = 237,568 u16; end = 19,636,736 < 19,924,480. OK.
    float* Opart = (float*)(ws + 4194816);
    float* Lpart = (float*)(ws + 4194816 + 15204352);
    unsigned* cnt = (unsigned*)(ws + 19701760);    // 8 x 4B per-XCD queue counters

    prep<<<dim3(8192), 256, 0, stream>>>(inputs, inB, W_in, WtB, W_out, WotB);
    gemm_tn<false><<<dim3(24, 32), 256, 0, stream>>>(inB, WtB, qkv, 4096, 3072, 1024);
    rope_vt<<<dim3(3072), 256, 0, stream>>>(qkv, segpos, Qh, Kh, Vt);
    hipMemsetAsync((void*)cnt, 0, 32, stream);
    attn_v14<<<dim3(768), 256, 0, stream>>>(Qh, Kh, Vt, x, Opart, Lpart, cnt);
    attn_reduce<<<dim3(32, 11), 256, 0, stream>>>(Opart, Lpart, x);
    gemm_tn<true><<<dim3(8, 32), 256, 0, stream>>>(x, WotB, out, 4096, 1024, 1024);
}

// Round 8
// 206.186 us; speedup vs baseline: 1.4513x; 1.4513x over previous
//
#include <hip/hip_runtime.h>

typedef unsigned short u16;
typedef __bf16 bf16x8 __attribute__((ext_vector_type(8)));
typedef float f32x4 __attribute__((ext_vector_type(4)));

__device__ __forceinline__ float b2f(u16 x) {
    union { float f; unsigned u; } v; v.u = ((unsigned)x) << 16; return v.f;
}
__device__ __forceinline__ u16 f2b(float f) {
    union { float f; unsigned u; } v; v.f = f;
    unsigned u = v.u;
    return (u16)((u + 0x7FFFu + ((u >> 16) & 1u)) >> 16);
}
// pack two f32 -> two truncated bf16 in one dword (lo=a, hi=b)
__device__ __forceinline__ unsigned pk2(float a, float b) {
    unsigned ua = __float_as_uint(a), ub = __float_as_uint(b);
    return (ub & 0xFFFF0000u) | (ua >> 16);
}
__device__ __forceinline__ f32x4 mfma_16x16x32(bf16x8 a, bf16x8 b, f32x4 c) {
    return __builtin_amdgcn_mfma_f32_16x16x32_bf16(a, b, c, 0, 0, 0);
}
// async global->LDS, 16B per lane. LDS dest = wave-uniform base + lane*16.
__device__ __forceinline__ void gld_lds16(const u16* g, u16* l) {
    __builtin_amdgcn_global_load_lds(
        (const __attribute__((address_space(1))) unsigned int*)g,
        (__attribute__((address_space(3))) unsigned int*)l,
        16, 0, 0);
}

#define VSTRIDE 2080
#define LOG2E 1.44269504f

// ---------------------------------------------------------------------------
// prep: inputs f32->bf16 [0,4096); W_in T+cvt [4096,7168); W_out T+cvt [7168,8192)
// ---------------------------------------------------------------------------
__global__ __launch_bounds__(256) void prep(const float* __restrict__ inputs,
                                            u16* __restrict__ inB,
                                            const float* __restrict__ W_in,
                                            u16* __restrict__ WtB,
                                            const float* __restrict__ W_out,
                                            u16* __restrict__ WotB) {
    __shared__ float T[32][33];
    const int bx = blockIdx.x;
    if (bx < 4096) {
        int i = (bx * 256 + threadIdx.x) * 4;
        float4 v = *(const float4*)(inputs + i);
        ushort4 o;
        o.x = f2b(v.x); o.y = f2b(v.y); o.z = f2b(v.z); o.w = f2b(v.w);
        *(ushort4*)(inB + i) = o;
        return;
    }
    const float* src; u16* dst; int R, C, c0, r0;
    if (bx < 7168) {
        int t = bx - 4096; src = W_in; dst = WtB; R = 1024; C = 3072;
        c0 = (t % 96) * 32; r0 = (t / 96) * 32;
    } else {
        int t = bx - 7168; src = W_out; dst = WotB; R = 1024; C = 1024;
        c0 = (t % 32) * 32; r0 = (t / 32) * 32;
    }
    int tr = threadIdx.x >> 5, tc = threadIdx.x & 31;
#pragma unroll
    for (int p = 0; p < 4; ++p)
        T[tr + p * 8][tc] = src[(size_t)(r0 + tr + p * 8) * C + c0 + tc];
    __syncthreads();
#pragma unroll
    for (int p = 0; p < 4; ++p)
        dst[(size_t)(c0 + tr + p * 8) * R + r0 + tc] = f2b(T[tc][tr + p * 8]);
}

// ---------------------------------------------------------------------------
// GEMM: C[M,N] = A[M,K] * Bt[N,K]^T. bf16 in, f32 accum.
// v15: 2-phase pipelined staging (double-buffered LDS, counted vmcnt, raw
// s_barrier) -- same discipline as the verified attn loop. BM templated:
// 128 (gemm1) or 64 (gemm2: grid 512 = 2 blocks/CU instead of 1).
// ---------------------------------------------------------------------------
template <int BM, bool F32OUT>
__global__ __launch_bounds__(256) void gemm_tn(const u16* __restrict__ A,
                                               const u16* __restrict__ Bt,
                                               void* __restrict__ Cv,
                                               int M, int N, int K) {
    __shared__ u16 As[2][BM * 32];
    __shared__ u16 Bs[2][128 * 32];
    const int tid = threadIdx.x;
    const int m0 = blockIdx.y * BM;
    const int n0 = blockIdx.x * 128;
    const int w = tid >> 6, lane = tid & 63;
    const int col16 = lane & 15, quad = lane >> 4;
    constexpr int MI = BM / 32;                  // 4 for BM=128, 2 for BM=64
    const int wm = (w >> 1) * (BM / 2), wn = (w & 1) * 64;
    const int srow = (lane >> 2), sseg = (lane & 3) * 8;

    f32x4 acc[MI][4];
#pragma unroll
    for (int i = 0; i < MI; ++i)
#pragma unroll
        for (int j = 0; j < 4; ++j) acc[i][j] = (f32x4){0.f, 0.f, 0.f, 0.f};

    // ---- prologue: stage k-step 0 into buf 0 ----
    if (BM == 128) {
#pragma unroll
        for (int cc = 0; cc < 2; ++cc) {
            int c = w * 2 + cc, row = c * 16 + srow;
            gld_lds16(A + (size_t)(m0 + row) * K + sseg, &As[0][c * 512 + lane * 8]);
            gld_lds16(Bt + (size_t)(n0 + row) * K + sseg, &Bs[0][c * 512 + lane * 8]);
        }
    } else {
        int row = w * 16 + srow;
        gld_lds16(A + (size_t)(m0 + row) * K + sseg, &As[0][w * 512 + lane * 8]);
#pragma unroll
        for (int cc = 0; cc < 2; ++cc) {
            int c = w * 2 + cc, rowb = c * 16 + srow;
            gld_lds16(Bt + (size_t)(n0 + rowb) * K + sseg, &Bs[0][c * 512 + lane * 8]);
        }
    }

    const int NK = K >> 5;
    for (int ki = 0; ki < NK; ++ki) {
        const int cur = ki & 1;
        if (ki + 1 < NK) {
            const int kt = (ki + 1) << 5;
            // ---- stage next k-step into the other buffer ----
            if (BM == 128) {
#pragma unroll
                for (int cc = 0; cc < 2; ++cc) {
                    int c = w * 2 + cc, row = c * 16 + srow;
                    gld_lds16(A + (size_t)(m0 + row) * K + kt + sseg, &As[cur ^ 1][c * 512 + lane * 8]);
                    gld_lds16(Bt + (size_t)(n0 + row) * K + kt + sseg, &Bs[cur ^ 1][c * 512 + lane * 8]);
                }
                asm volatile("s_waitcnt vmcnt(4)" ::: "memory");
            } else {
                int row = w * 16 + srow;
                gld_lds16(A + (size_t)(m0 + row) * K + kt + sseg, &As[cur ^ 1][w * 512 + lane * 8]);
#pragma unroll
                for (int cc = 0; cc < 2; ++cc) {
                    int c = w * 2 + cc, rowb = c * 16 + srow;
                    gld_lds16(Bt + (size_t)(n0 + rowb) * K + kt + sseg, &Bs[cur ^ 1][c * 512 + lane * 8]);
                }
                asm volatile("s_waitcnt vmcnt(3)" ::: "memory");
            }
        } else {
            asm volatile("s_waitcnt vmcnt(0)" ::: "memory");
        }
        asm volatile("s_barrier" ::: "memory");

        bf16x8 af[MI], bfr[4];
#pragma unroll
        for (int i = 0; i < MI; ++i)
            af[i] = *(const bf16x8*)&As[cur][(wm + i * 16 + col16) * 32 + quad * 8];
#pragma unroll
        for (int j = 0; j < 4; ++j)
            bfr[j] = *(const bf16x8*)&Bs[cur][(wn + j * 16 + col16) * 32 + quad * 8];
#pragma unroll
        for (int i = 0; i < MI; ++i)
#pragma unroll
            for (int j = 0; j < 4; ++j)
                acc[i][j] = mfma_16x16x32(af[i], bfr[j], acc[i][j]);

        // LDS reads of buf[cur] done before next iteration overwrites it
        asm volatile("s_waitcnt lgkmcnt(0)" ::: "memory");
        asm volatile("s_barrier" ::: "memory");
    }

#pragma unroll
    for (int i = 0; i < MI; ++i) {
#pragma unroll
        for (int r = 0; r < 4; ++r) {
            int m = m0 + wm + i * 16 + quad * 4 + r;
            if (F32OUT) {
                float* Crow = (float*)Cv + (size_t)m * N + n0 + wn;
#pragma unroll
                for (int j = 0; j < 4; ++j)
                    Crow[j * 16 + col16] = acc[i][j][r];
            } else {
                u16* Crow = (u16*)Cv + (size_t)m * N + n0 + wn;
#pragma unroll
                for (int j = 0; j < 4; ++j)
                    Crow[j * 16 + col16] = f2b(acc[i][j][r]);
            }
        }
    }
}

// ---------------------------------------------------------------------------
// Fused rope + v_transpose. blocks [0,1024): RoPE (q scaled log2e/8);
// blocks [1024,3072): V transpose into Vt [BH][64][VSTRIDE].
// ---------------------------------------------------------------------------
__global__ __launch_bounds__(256) void rope_vt(const u16* __restrict__ qkv,
                                               const int* __restrict__ segpos,
                                               u16* __restrict__ Qh,
                                               u16* __restrict__ Kh,
                                               u16* __restrict__ Vt) {
    __shared__ u16 T[32][72];
    const int bx = blockIdx.x;
    if (bx < 1024) {
        int t = bx * 256 + threadIdx.x;
        int seg = t & 3;
        int h = (t >> 2) & 15;
        int row = t >> 6;
        float pos = (float)segpos[row];
        const u16* base = qkv + (size_t)row * 3072 + h * 192 + seg * 8;
        union { uint4 u; u16 s[8]; } q1, q2, k1, k2, oq1, oq2, ok1, ok2;
        q1.u = *(const uint4*)(base);
        q2.u = *(const uint4*)(base + 32);
        k1.u = *(const uint4*)(base + 64);
        k2.u = *(const uint4*)(base + 96);
        const float qs = 0.125f * LOG2E;
#pragma unroll
        for (int j = 0; j < 8; ++j) {
            int d = seg * 8 + j;
            float inv_freq = __expf(-(float)d * (9.210340371976184f / 32.0f));
            float ang = pos * inv_freq;
            float c = __cosf(ang), s = __sinf(ang);
            float a1 = b2f(q1.s[j]), a2 = b2f(q2.s[j]);
            float b1 = b2f(k1.s[j]), b2v = b2f(k2.s[j]);
            oq1.s[j] = f2b((a1 * c - a2 * s) * qs);
            oq2.s[j] = f2b((a1 * s + a2 * c) * qs);
            ok1.s[j] = f2b(b1 * c - b2v * s);
            ok2.s[j] = f2b(b1 * s + b2v * c);
        }
        int b = row >> 11, srow = row & 2047;
        size_t idx = ((size_t)(b * 16 + h) * 2048 + srow) * 64 + seg * 8;
        *(uint4*)&Qh[idx]      = oq1.u;
        *(uint4*)&Qh[idx + 32] = oq2.u;
        *(uint4*)&Kh[idx]      = ok1.u;
        *(uint4*)&Kh[idx + 32] = ok2.u;
        return;
    }
    int bxx = bx - 1024;
    int s0 = (bxx & 63) * 32;
    int bh = bxx >> 6;
    int b = bh >> 4, h = bh & 15;
    int t = threadIdx.x;
    {
        int r = t >> 3, seg = t & 7;
        const u16* src = qkv + (size_t)(b * 2048 + s0 + r) * 3072 + h * 192 + 128 + seg * 8;
        *(uint4*)&T[r][seg * 8] = *(const uint4*)src;
    }
    __syncthreads();
    {
        int d = t >> 2, ss = (t & 3) * 8;
        union { uint4 u; u16 s[8]; } w;
#pragma unroll
        for (int j = 0; j < 8; ++j) w.s[j] = T[ss + j][d];
        *(uint4*)(Vt + (size_t)bh * 64 * VSTRIDE + (size_t)d * VSTRIDE + s0 + ss) = w.u;
    }
}

// ---------------------------------------------------------------------------
// Flash attention v9 (verified best: 46.7us): split-K, fixed-max base-2
// softmax => partial (O,l) combine by pure addition. 27 units/bh (<=14
// chunks), grid 864 = 32 bh x 27, XCD-swizzled (4 bh/XCD, K/V L2-resident),
// units heaviest-first (LPT). 2-phase gld_lds pipeline, vmcnt(4), XOR swizzle.
// ---------------------------------------------------------------------------
#define FIXED_M2 34.6246561f    // 24 * log2(e)

// per-bh unit tables, execution-ordered by descending chunk count (LPT).
__device__ const int UTQ[27] = {6,7,8,9,10,11,12,13,13,14,14,15,15, 5,12, 4,11, 3,10, 2,9, 1,8,15, 0,7,14};
__device__ const int UK0[27] = {0,0,0,0,0,0,0,0,14,0,14,0,14, 0,14, 0,14, 0,14, 0,14, 0,14,28, 0,14,28};
__device__ const int UNC[27] = {14,14,14,14,14,14,14,14,14,14,14,14,14, 12,12, 10,10, 8,8, 6,6, 4,4,4, 2,2,2};
__device__ const int UPS[27] = {-1,0,1,2,3,4,5,6,7,8,9,10,11, -1,12, -1,13, -1,14, -1,15, -1,16,17, -1,18,19};
// reduce tables: tiles tq = 7 + ti, ti in [0,9)
__device__ const int RUN[9]    = {2,2,2,2,2,2,2,3,3};
__device__ const int RUS[9][3] = {{0,18,-1},{1,16,-1},{2,15,-1},{3,14,-1},{4,13,-1},
                                  {5,12,-1},{6,7,-1},{8,9,19},{10,11,17}};

__global__ __launch_bounds__(256) void attn_v9(const u16* __restrict__ Qh,
                                               const u16* __restrict__ Kh,
                                               const u16* __restrict__ Vt,
                                               u16* __restrict__ X,
                                               float* __restrict__ Opart,
                                               float* __restrict__ Lpart) {
    __shared__ u16 Ks[2][64 * 64];   // [buf][k-row][64 d]  (8KB/buf)
    __shared__ u16 Vs[2][64 * 64];   // [buf][d-row][64 k]  (8KB/buf)
    __shared__ u16 Ps[4][32 * 64];   // wave-private P [q][64 k], swizzled
    __shared__ float lred[4][32];
    const int tid = threadIdx.x;
    const int w = tid >> 6, lane = tid & 63;
    const int col16 = lane & 15, quad = lane >> 4;
    // XCD-aware block swizzle: 864 = 8 XCD x 108; each XCD owns 4 bh.
    const int raw = blockIdx.x;
    const int bsw = (raw & 7) * 108 + (raw >> 3);
    const int bh = bsw / 27;
    const int slot = bsw - bh * 27;
    const int tq = UTQ[slot];
    const int c0 = UK0[slot];
    const int nc = UNC[slot];
    const int ps = UPS[slot];
    const int q0 = tq * 128 + w * 32;
    const u16* Qp = Qh + (size_t)bh * 2048 * 64;
    const u16* Kp = Kh + (size_t)bh * 2048 * 64;
    const u16* Vp = Vt + (size_t)bh * 64 * VSTRIDE;
    u16* Pw = Ps[w];
    const int swz = (col16 & 7) << 3;      // row-XOR for all LDS tiles (u16 units)

    // Q fragments (used as B-operand of K*Q^T -- identical lane data)
    bf16x8 qa[2][2];
#pragma unroll
    for (int t = 0; t < 2; ++t)
#pragma unroll
        for (int hf = 0; hf < 2; ++hf)
            qa[t][hf] = *(const bf16x8*)&Qp[(size_t)(q0 + t * 16 + col16) * 64 + hf * 32 + quad * 8];

    float l_acc[2] = {0.f, 0.f};
    f32x4 o[2][4];
#pragma unroll
    for (int t = 0; t < 2; ++t)
#pragma unroll
        for (int f = 0; f < 4; ++f) o[t][f] = (f32x4){0.f, 0.f, 0.f, 0.f};

    // staging decomposition: each gld_lds covers 8 rows x 128B; lane = r*8+s.
    // swizzled granule: global slot = s ^ r  (involution; read applies same XOR)
    const int sr = lane >> 3;              // row within instr (0..7)
    const int sg = ((lane & 7) ^ sr) * 8;  // pre-swizzled 16B granule (u16 units)

    // ---- prologue: stage chunk c0 into buf 0 (4 instrs/wave: 2 K + 2 V) ----
    {
        const int k0 = c0 * 64;
#pragma unroll
        for (int i = 0; i < 2; ++i) {
            int c = w * 2 + i;
            gld_lds16(Kp + (size_t)(k0 + c * 8 + sr) * 64 + sg, &Ks[0][c * 512 + lane * 8]);
        }
#pragma unroll
        for (int i = 0; i < 2; ++i) {
            int c = w * 2 + i;
            gld_lds16(Vp + (size_t)(c * 8 + sr) * VSTRIDE + k0 + sg, &Vs[0][c * 512 + lane * 8]);
        }
    }

    for (int ci = 0; ci < nc; ++ci) {
        const int cur = ci & 1;
        const u16* KsC = Ks[cur];
        const u16* VsC = Vs[cur];

        // ---- issue next chunk's stage into the other buffer ----
        if (ci + 1 < nc) {
            const int k0n = (c0 + ci + 1) * 64;
            u16* Kd = Ks[cur ^ 1];
            u16* Vd = Vs[cur ^ 1];
#pragma unroll
            for (int i = 0; i < 2; ++i) {
                int c = w * 2 + i;
                gld_lds16(Kp + (size_t)(k0n + c * 8 + sr) * 64 + sg, Kd + c * 512 + lane * 8);
            }
#pragma unroll
            for (int i = 0; i < 2; ++i) {
                int c = w * 2 + i;
                gld_lds16(Vp + (size_t)(c * 8 + sr) * VSTRIDE + k0n + sg, Vd + c * 512 + lane * 8);
            }
            // wait only for CURRENT chunk's 4 loads; next chunk's 4 stay in flight
            asm volatile("s_waitcnt vmcnt(4)" ::: "memory");
        } else {
            asm volatile("s_waitcnt vmcnt(0)" ::: "memory");
        }
        asm volatile("s_barrier" ::: "memory");

        const int k0 = (c0 + ci) * 64;

        // ---- K*Q^T -> S^T ----
        f32x4 s[2][4];
#pragma unroll
        for (int t = 0; t < 2; ++t)
#pragma unroll
            for (int kt = 0; kt < 4; ++kt) s[t][kt] = (f32x4){0.f, 0.f, 0.f, 0.f};
#pragma unroll
        for (int kt = 0; kt < 4; ++kt) {
            const u16* kb = &KsC[(kt * 16 + col16) * 64];
            bf16x8 kf0 = *(const bf16x8*)&kb[(quad * 8) ^ swz];
            bf16x8 kf1 = *(const bf16x8*)&kb[(32 + quad * 8) ^ swz];
            s[0][kt] = mfma_16x16x32(kf0, qa[0][0], s[0][kt]);
            s[0][kt] = mfma_16x16x32(kf1, qa[0][1], s[0][kt]);
            s[1][kt] = mfma_16x16x32(kf0, qa[1][0], s[1][kt]);
            s[1][kt] = mfma_16x16x32(kf1, qa[1][1], s[1][kt]);
        }

        // ---- softmax: p = 2^(s - M2), per-lane l, packed dword P writes ----
        const bool domask = (k0 + 63 > q0);
#pragma unroll
        for (int t = 0; t < 2; ++t) {
            const int qg = q0 + t * 16 + col16;
            float rs = 0.f;
#pragma unroll
            for (int kt = 0; kt < 4; ++kt) {
                float p[4];
#pragma unroll
                for (int r = 0; r < 4; ++r) {
                    float sv = s[t][kt][r];
                    if (domask && (k0 + kt * 16 + quad * 4 + r > qg)) sv = -1e30f;
                    p[r] = __builtin_amdgcn_exp2f(sv - FIXED_M2);
                    rs += p[r];
                }
                unsigned* prow = (unsigned*)&Pw[(t * 16 + col16) * 64 + ((kt * 16 + quad * 4) ^ swz)];
                prow[0] = pk2(p[0], p[1]);
                prow[1] = pk2(p[2], p[3]);
            }
            l_acc[t] += rs;
        }
        asm volatile("s_waitcnt lgkmcnt(0)" ::: "memory");  // P writes -> reads

        // ---- PV: 16 MFMAs ----
#pragma unroll
        for (int ss = 0; ss < 2; ++ss) {
            const int ko = (ss * 32 + quad * 8) ^ swz;
            bf16x8 pf0 = *(const bf16x8*)&Pw[(col16) * 64 + ko];
            bf16x8 pf1 = *(const bf16x8*)&Pw[(16 + col16) * 64 + ko];
#pragma unroll
            for (int f = 0; f < 4; ++f) {
                bf16x8 vf = *(const bf16x8*)&VsC[(f * 16 + col16) * 64 + ko];
                o[0][f] = mfma_16x16x32(pf0, vf, o[0][f]);
                o[1][f] = mfma_16x16x32(pf1, vf, o[1][f]);
            }
        }
        // all LDS reads of buf[cur] complete before next staging overwrites
        asm volatile("s_waitcnt lgkmcnt(0)" ::: "memory");
        asm volatile("s_barrier" ::: "memory");
    }

    // ---- l reduction across quads (butterfly -> every lane has row total) ----
    float lt[2];
#pragma unroll
    for (int t = 0; t < 2; ++t) {
        float l = l_acc[t];
        l += __shfl_xor(l, 16);
        l += __shfl_xor(l, 32);
        lt[t] = l;
        if (quad == 0) lred[w][t * 16 + col16] = l;
    }
    asm volatile("s_waitcnt lgkmcnt(0)" ::: "memory");

    if (ps >= 0) {
        // ---- partial epilogue: raw O (no divide) + l to workspace ----
        const int pg = bh * 20 + ps;
        float* Op = Opart + ((size_t)pg * 128 + w * 32) * 64;
#pragma unroll
        for (int t = 0; t < 2; ++t) {
#pragma unroll
            for (int r = 0; r < 4; ++r) {
                float* Crow = Op + (t * 16 + quad * 4 + r) * 64;
#pragma unroll
                for (int f = 0; f < 4; ++f)
                    Crow[f * 16 + col16] = o[t][f][r];
            }
        }
        if (quad == 0) {
            float* Lp = Lpart + (size_t)pg * 128 + w * 32;
#pragma unroll
            for (int t = 0; t < 2; ++t) Lp[t * 16 + col16] = lt[t];
        }
        return;
    }

    // ---- direct epilogue (single-unit tile): divide and write X ----
    const int b = bh >> 4, h = bh & 15;
#pragma unroll
    for (int t = 0; t < 2; ++t) {
#pragma unroll
        for (int r = 0; r < 4; ++r) {
            float inv = 1.0f / lred[w][t * 16 + quad * 4 + r];
            int srow = q0 + t * 16 + quad * 4 + r;
            u16* Xp = X + ((size_t)(b * 2048 + srow)) * 1024 + h * 64;
#pragma unroll
            for (int f = 0; f < 4; ++f)
                Xp[f * 16 + col16] = f2b(o[t][f][r] * inv);
        }
    }
}

// ---------------------------------------------------------------------------
// attn_reduce: combine 2-3 partials per (bh, tq in 7..15): X = (sum O)/(sum l)
// ---------------------------------------------------------------------------
__global__ __launch_bounds__(256) void attn_reduce(const float* __restrict__ Opart,
                                                   const float* __restrict__ Lpart,
                                                   u16* __restrict__ X) {
    const int bh = blockIdx.x;           // 0..31
    const int ti = blockIdx.y;           // 0..8 -> tq = 7+ti
    const int tq = 7 + ti;
    const int tid = threadIdx.x;
    const int b = bh >> 4, h = bh & 15;
    const int np = RUN[ti];
    const size_t g0 = (size_t)(bh * 20 + RUS[ti][0]);
    const size_t g1 = (size_t)(bh * 20 + RUS[ti][1]);
    const size_t g2 = (np > 2) ? (size_t)(bh * 20 + RUS[ti][2]) : 0;
    const float4* O0 = (const float4*)Opart + g0 * 2048;
    const float4* O1 = (const float4*)Opart + g1 * 2048;
    const float4* O2 = (const float4*)Opart + g2 * 2048;
#pragma unroll
    for (int i = 0; i < 8; ++i) {
        int e4 = i * 256 + tid;          // float4 index within 128x64 tile
        int q = e4 >> 4, d0 = (e4 & 15) * 4;
        float4 a = O0[e4];
        float4 c = O1[e4];
        a.x += c.x; a.y += c.y; a.z += c.z; a.w += c.w;
        float l = Lpart[g0 * 128 + q] + Lpart[g1 * 128 + q];
        if (np > 2) {
            float4 d = O2[e4];
            a.x += d.x; a.y += d.y; a.z += d.z; a.w += d.w;
            l += Lpart[g2 * 128 + q];
        }
        float inv = 1.0f / l;
        ushort4 ov;
        ov.x = f2b(a.x * inv); ov.y = f2b(a.y * inv);
        ov.z = f2b(a.z * inv); ov.w = f2b(a.w * inv);
        *(ushort4*)&X[((size_t)(b * 2048 + tq * 128 + q)) * 1024 + h * 64 + d0] = ov;
    }
}

// ---------------------------------------------------------------------------
// launch
// ---------------------------------------------------------------------------
extern "C" void kernel_launch(void* const* d_in, const int* in_sizes, int n_in,
                              void* d_out, int out_size, void* d_ws, size_t ws_size,
                              hipStream_t stream) {
    const float* inputs = (const float*)d_in[0];
    const int* segpos   = (const int*)d_in[1];
    const float* W_in   = (const float*)d_in[3];
    const float* W_out  = (const float*)d_in[4];
    float* out = (float*)d_out;

    u16* ws = (u16*)d_ws;
    u16* qkv   = ws;                               // 4096*3072 bf16
    u16* x     = qkv;                              // alias (qkv dead after rope_vt)
    u16* inB   = qkv + 12582912 + 512;
    u16* WtB   = inB + 4194304 + 512;              // W_in^T  [3072][1024]
    u16* WotB  = WtB + 3145728 + 512;              // W_out^T [1024][1024]
    u16* Qh    = WotB + 1048576 + 512;             // [BH][S][64]
    u16* Kh    = Qh + 4194304 + 512;
    u16* Vt    = Kh + 4194304 + 512;               // [BH][64][VSTRIDE]
    // split-K partials live in qkv[8.39M..]/inB/WtB space (dead during attn):
    // Opart: 640 slots x 128 x 64 f32 = 10,485,760 u16; Lpart: 640 x 128 f32.
    float* Opart = (float*)(ws + 8388608);
    float* Lpart = (float*)(ws + 8388608 + 10485760);

    prep<<<dim3(8192), 256, 0, stream>>>(inputs, inB, W_in, WtB, W_out, WotB);
    gemm_tn<128, false><<<dim3(24, 32), 256, 0, stream>>>(inB, WtB, qkv, 4096, 3072, 1024);
    rope_vt<<<dim3(3072), 256, 0, stream>>>(qkv, segpos, Qh, Kh, Vt);
    attn_v9<<<dim3(864), 256, 0, stream>>>(Qh, Kh, Vt, x, Opart, Lpart);
    attn_reduce<<<dim3(32, 9), 256, 0, stream>>>(Opart, Lpart, x);
    gemm_tn<64, true><<<dim3(8, 64), 256, 0, stream>>>(x, WotB, out, 4096, 1024, 1024);
}

// Round 9
// 201.337 us; speedup vs baseline: 1.4863x; 1.0241x over previous
//
#include <hip/hip_runtime.h>

typedef unsigned short u16;
typedef __bf16 bf16x8 __attribute__((ext_vector_type(8)));
typedef float f32x4 __attribute__((ext_vector_type(4)));

__device__ __forceinline__ float b2f(u16 x) {
    union { float f; unsigned u; } v; v.u = ((unsigned)x) << 16; return v.f;
}
__device__ __forceinline__ u16 f2b(float f) {
    union { float f; unsigned u; } v; v.f = f;
    unsigned u = v.u;
    return (u16)((u + 0x7FFFu + ((u >> 16) & 1u)) >> 16);
}
// pack two f32 -> two truncated bf16 in one dword (lo=a, hi=b)
__device__ __forceinline__ unsigned pk2(float a, float b) {
    unsigned ua = __float_as_uint(a), ub = __float_as_uint(b);
    return (ub & 0xFFFF0000u) | (ua >> 16);
}
__device__ __forceinline__ f32x4 mfma_16x16x32(bf16x8 a, bf16x8 b, f32x4 c) {
    return __builtin_amdgcn_mfma_f32_16x16x32_bf16(a, b, c, 0, 0, 0);
}
// async global->LDS, 16B per lane. LDS dest = wave-uniform base + lane*16.
__device__ __forceinline__ void gld_lds16(const u16* g, u16* l) {
    __builtin_amdgcn_global_load_lds(
        (const __attribute__((address_space(1))) unsigned int*)g,
        (__attribute__((address_space(3))) unsigned int*)l,
        16, 0, 0);
}

#define VSTRIDE 2080
#define LOG2E 1.44269504f

// ---------------------------------------------------------------------------
// prep: inputs f32->bf16 [0,4096); W_in T+cvt [4096,7168); W_out T+cvt [7168,8192)
// ---------------------------------------------------------------------------
__global__ __launch_bounds__(256) void prep(const float* __restrict__ inputs,
                                            u16* __restrict__ inB,
                                            const float* __restrict__ W_in,
                                            u16* __restrict__ WtB,
                                            const float* __restrict__ W_out,
                                            u16* __restrict__ WotB) {
    __shared__ float T[32][33];
    const int bx = blockIdx.x;
    if (bx < 4096) {
        int i = (bx * 256 + threadIdx.x) * 4;
        float4 v = *(const float4*)(inputs + i);
        ushort4 o;
        o.x = f2b(v.x); o.y = f2b(v.y); o.z = f2b(v.z); o.w = f2b(v.w);
        *(ushort4*)(inB + i) = o;
        return;
    }
    const float* src; u16* dst; int R, C, c0, r0;
    if (bx < 7168) {
        int t = bx - 4096; src = W_in; dst = WtB; R = 1024; C = 3072;
        c0 = (t % 96) * 32; r0 = (t / 96) * 32;
    } else {
        int t = bx - 7168; src = W_out; dst = WotB; R = 1024; C = 1024;
        c0 = (t % 32) * 32; r0 = (t / 32) * 32;
    }
    int tr = threadIdx.x >> 5, tc = threadIdx.x & 31;
#pragma unroll
    for (int p = 0; p < 4; ++p)
        T[tr + p * 8][tc] = src[(size_t)(r0 + tr + p * 8) * C + c0 + tc];
    __syncthreads();
#pragma unroll
    for (int p = 0; p < 4; ++p)
        dst[(size_t)(c0 + tr + p * 8) * R + r0 + tc] = f2b(T[tc][tr + p * 8]);
}

// ---------------------------------------------------------------------------
// GEMM (gemm1): C[M,N] = A[M,K] * Bt[N,K]^T. bf16 in, 2-phase pipelined
// staging (double-buffered LDS, counted vmcnt, raw s_barrier). BM=128.
// ---------------------------------------------------------------------------
template <int BM, bool F32OUT>
__global__ __launch_bounds__(256) void gemm_tn(const u16* __restrict__ A,
                                               const u16* __restrict__ Bt,
                                               void* __restrict__ Cv,
                                               int M, int N, int K) {
    __shared__ u16 As[2][BM * 32];
    __shared__ u16 Bs[2][128 * 32];
    const int tid = threadIdx.x;
    const int m0 = blockIdx.y * BM;
    const int n0 = blockIdx.x * 128;
    const int w = tid >> 6, lane = tid & 63;
    const int col16 = lane & 15, quad = lane >> 4;
    constexpr int MI = BM / 32;                  // 4 for BM=128
    const int wm = (w >> 1) * (BM / 2), wn = (w & 1) * 64;
    const int srow = (lane >> 2), sseg = (lane & 3) * 8;

    f32x4 acc[MI][4];
#pragma unroll
    for (int i = 0; i < MI; ++i)
#pragma unroll
        for (int j = 0; j < 4; ++j) acc[i][j] = (f32x4){0.f, 0.f, 0.f, 0.f};

    // ---- prologue: stage k-step 0 into buf 0 ----
    if (BM == 128) {
#pragma unroll
        for (int cc = 0; cc < 2; ++cc) {
            int c = w * 2 + cc, row = c * 16 + srow;
            gld_lds16(A + (size_t)(m0 + row) * K + sseg, &As[0][c * 512 + lane * 8]);
            gld_lds16(Bt + (size_t)(n0 + row) * K + sseg, &Bs[0][c * 512 + lane * 8]);
        }
    } else {
        int row = w * 16 + srow;
        gld_lds16(A + (size_t)(m0 + row) * K + sseg, &As[0][w * 512 + lane * 8]);
#pragma unroll
        for (int cc = 0; cc < 2; ++cc) {
            int c = w * 2 + cc, rowb = c * 16 + srow;
            gld_lds16(Bt + (size_t)(n0 + rowb) * K + sseg, &Bs[0][c * 512 + lane * 8]);
        }
    }

    const int NK = K >> 5;
    for (int ki = 0; ki < NK; ++ki) {
        const int cur = ki & 1;
        if (ki + 1 < NK) {
            const int kt = (ki + 1) << 5;
            // ---- stage next k-step into the other buffer ----
            if (BM == 128) {
#pragma unroll
                for (int cc = 0; cc < 2; ++cc) {
                    int c = w * 2 + cc, row = c * 16 + srow;
                    gld_lds16(A + (size_t)(m0 + row) * K + kt + sseg, &As[cur ^ 1][c * 512 + lane * 8]);
                    gld_lds16(Bt + (size_t)(n0 + row) * K + kt + sseg, &Bs[cur ^ 1][c * 512 + lane * 8]);
                }
                asm volatile("s_waitcnt vmcnt(4)" ::: "memory");
            } else {
                int row = w * 16 + srow;
                gld_lds16(A + (size_t)(m0 + row) * K + kt + sseg, &As[cur ^ 1][w * 512 + lane * 8]);
#pragma unroll
                for (int cc = 0; cc < 2; ++cc) {
                    int c = w * 2 + cc, rowb = c * 16 + srow;
                    gld_lds16(Bt + (size_t)(n0 + rowb) * K + kt + sseg, &Bs[cur ^ 1][c * 512 + lane * 8]);
                }
                asm volatile("s_waitcnt vmcnt(3)" ::: "memory");
            }
        } else {
            asm volatile("s_waitcnt vmcnt(0)" ::: "memory");
        }
        asm volatile("s_barrier" ::: "memory");

        bf16x8 af[MI], bfr[4];
#pragma unroll
        for (int i = 0; i < MI; ++i)
            af[i] = *(const bf16x8*)&As[cur][(wm + i * 16 + col16) * 32 + quad * 8];
#pragma unroll
        for (int j = 0; j < 4; ++j)
            bfr[j] = *(const bf16x8*)&Bs[cur][(wn + j * 16 + col16) * 32 + quad * 8];
#pragma unroll
        for (int i = 0; i < MI; ++i)
#pragma unroll
            for (int j = 0; j < 4; ++j)
                acc[i][j] = mfma_16x16x32(af[i], bfr[j], acc[i][j]);

        // LDS reads of buf[cur] done before next iteration overwrites it
        asm volatile("s_waitcnt lgkmcnt(0)" ::: "memory");
        asm volatile("s_barrier" ::: "memory");
    }

#pragma unroll
    for (int i = 0; i < MI; ++i) {
#pragma unroll
        for (int r = 0; r < 4; ++r) {
            int m = m0 + wm + i * 16 + quad * 4 + r;
            if (F32OUT) {
                float* Crow = (float*)Cv + (size_t)m * N + n0 + wn;
#pragma unroll
                for (int j = 0; j < 4; ++j)
                    Crow[j * 16 + col16] = acc[i][j][r];
            } else {
                u16* Crow = (u16*)Cv + (size_t)m * N + n0 + wn;
#pragma unroll
                for (int j = 0; j < 4; ++j)
                    Crow[j * 16 + col16] = f2b(acc[i][j][r]);
            }
        }
    }
}

// ---------------------------------------------------------------------------
// gemm2 (v16): C[M,N](f32) = A[M,K] * Bt[N,K]^T, BM=64 x BN=64 x BK=64.
// Grid (N/64, M/64) = 1024 = 4 blocks/CU all-resident (LDS 32KB, plain
// launch_bounds). 16 K-steps (half the barrier events of BK=32). 128B-row
// LDS tiles use attn's verified XOR swizzle: pre-swizzled global source
// (sg) for gld_lds + ^swz on fragment reads (both-sides involution).
// ---------------------------------------------------------------------------
__global__ __launch_bounds__(256) void gemm_tn64(const u16* __restrict__ A,
                                                 const u16* __restrict__ Bt,
                                                 float* __restrict__ C,
                                                 int M, int N, int K) {
    __shared__ u16 As[2][64 * 64];   // [buf][row][64 k]  (8KB/buf)
    __shared__ u16 Bs[2][64 * 64];
    const int tid = threadIdx.x;
    const int m0 = blockIdx.y * 64;
    const int n0 = blockIdx.x * 64;
    const int w = tid >> 6, lane = tid & 63;
    const int col16 = lane & 15, quad = lane >> 4;
    const int wm = (w >> 1) * 32, wn = (w & 1) * 32;
    // staging decomposition: each gld_lds covers 8 rows x 128B; lane = r*8+s.
    const int sr = lane >> 3;              // row within instr (0..7)
    const int sg = ((lane & 7) ^ sr) * 8;  // pre-swizzled 16B granule (u16 units)
    const int swz = (col16 & 7) << 3;      // row-XOR on fragment reads

    f32x4 acc[2][2];
#pragma unroll
    for (int i = 0; i < 2; ++i)
#pragma unroll
        for (int j = 0; j < 2; ++j) acc[i][j] = (f32x4){0.f, 0.f, 0.f, 0.f};

    // ---- prologue: stage k-step 0 into buf 0 (4 instrs/wave: 2 A + 2 B) ----
#pragma unroll
    for (int i = 0; i < 2; ++i) {
        int c = w * 2 + i;
        gld_lds16(A + (size_t)(m0 + c * 8 + sr) * K + sg, &As[0][c * 512 + lane * 8]);
    }
#pragma unroll
    for (int i = 0; i < 2; ++i) {
        int c = w * 2 + i;
        gld_lds16(Bt + (size_t)(n0 + c * 8 + sr) * K + sg, &Bs[0][c * 512 + lane * 8]);
    }

    const int NK = K >> 6;                 // 16 steps
    for (int ki = 0; ki < NK; ++ki) {
        const int cur = ki & 1;
        if (ki + 1 < NK) {
            const int kt = (ki + 1) << 6;
#pragma unroll
            for (int i = 0; i < 2; ++i) {
                int c = w * 2 + i;
                gld_lds16(A + (size_t)(m0 + c * 8 + sr) * K + kt + sg, &As[cur ^ 1][c * 512 + lane * 8]);
            }
#pragma unroll
            for (int i = 0; i < 2; ++i) {
                int c = w * 2 + i;
                gld_lds16(Bt + (size_t)(n0 + c * 8 + sr) * K + kt + sg, &Bs[cur ^ 1][c * 512 + lane * 8]);
            }
            // wait only for CURRENT step's 4 loads; next step's 4 stay in flight
            asm volatile("s_waitcnt vmcnt(4)" ::: "memory");
        } else {
            asm volatile("s_waitcnt vmcnt(0)" ::: "memory");
        }
        asm volatile("s_barrier" ::: "memory");

#pragma unroll
        for (int ks = 0; ks < 2; ++ks) {
            const int ko = (ks * 32 + quad * 8) ^ swz;
            bf16x8 af[2], bfr[2];
#pragma unroll
            for (int i = 0; i < 2; ++i)
                af[i] = *(const bf16x8*)&As[cur][(wm + i * 16 + col16) * 64 + ko];
#pragma unroll
            for (int j = 0; j < 2; ++j)
                bfr[j] = *(const bf16x8*)&Bs[cur][(wn + j * 16 + col16) * 64 + ko];
#pragma unroll
            for (int i = 0; i < 2; ++i)
#pragma unroll
                for (int j = 0; j < 2; ++j)
                    acc[i][j] = mfma_16x16x32(af[i], bfr[j], acc[i][j]);
        }

        // LDS reads of buf[cur] done before next iteration overwrites it
        asm volatile("s_waitcnt lgkmcnt(0)" ::: "memory");
        asm volatile("s_barrier" ::: "memory");
    }

#pragma unroll
    for (int i = 0; i < 2; ++i) {
#pragma unroll
        for (int r = 0; r < 4; ++r) {
            int m = m0 + wm + i * 16 + quad * 4 + r;
            float* Crow = C + (size_t)m * N + n0 + wn;
#pragma unroll
            for (int j = 0; j < 2; ++j)
                Crow[j * 16 + col16] = acc[i][j][r];
        }
    }
}

// ---------------------------------------------------------------------------
// Fused rope + v_transpose. blocks [0,1024): RoPE (q scaled log2e/8);
// blocks [1024,3072): V transpose into Vt [BH][64][VSTRIDE].
// ---------------------------------------------------------------------------
__global__ __launch_bounds__(256) void rope_vt(const u16* __restrict__ qkv,
                                               const int* __restrict__ segpos,
                                               u16* __restrict__ Qh,
                                               u16* __restrict__ Kh,
                                               u16* __restrict__ Vt) {
    __shared__ u16 T[32][72];
    const int bx = blockIdx.x;
    if (bx < 1024) {
        int t = bx * 256 + threadIdx.x;
        int seg = t & 3;
        int h = (t >> 2) & 15;
        int row = t >> 6;
        float pos = (float)segpos[row];
        const u16* base = qkv + (size_t)row * 3072 + h * 192 + seg * 8;
        union { uint4 u; u16 s[8]; } q1, q2, k1, k2, oq1, oq2, ok1, ok2;
        q1.u = *(const uint4*)(base);
        q2.u = *(const uint4*)(base + 32);
        k1.u = *(const uint4*)(base + 64);
        k2.u = *(const uint4*)(base + 96);
        const float qs = 0.125f * LOG2E;
#pragma unroll
        for (int j = 0; j < 8; ++j) {
            int d = seg * 8 + j;
            float inv_freq = __expf(-(float)d * (9.210340371976184f / 32.0f));
            float ang = pos * inv_freq;
            float c = __cosf(ang), s = __sinf(ang);
            float a1 = b2f(q1.s[j]), a2 = b2f(q2.s[j]);
            float b1 = b2f(k1.s[j]), b2v = b2f(k2.s[j]);
            oq1.s[j] = f2b((a1 * c - a2 * s) * qs);
            oq2.s[j] = f2b((a1 * s + a2 * c) * qs);
            ok1.s[j] = f2b(b1 * c - b2v * s);
            ok2.s[j] = f2b(b1 * s + b2v * c);
        }
        int b = row >> 11, srow = row & 2047;
        size_t idx = ((size_t)(b * 16 + h) * 2048 + srow) * 64 + seg * 8;
        *(uint4*)&Qh[idx]      = oq1.u;
        *(uint4*)&Qh[idx + 32] = oq2.u;
        *(uint4*)&Kh[idx]      = ok1.u;
        *(uint4*)&Kh[idx + 32] = ok2.u;
        return;
    }
    int bxx = bx - 1024;
    int s0 = (bxx & 63) * 32;
    int bh = bxx >> 6;
    int b = bh >> 4, h = bh & 15;
    int t = threadIdx.x;
    {
        int r = t >> 3, seg = t & 7;
        const u16* src = qkv + (size_t)(b * 2048 + s0 + r) * 3072 + h * 192 + 128 + seg * 8;
        *(uint4*)&T[r][seg * 8] = *(const uint4*)src;
    }
    __syncthreads();
    {
        int d = t >> 2, ss = (t & 3) * 8;
        union { uint4 u; u16 s[8]; } w;
#pragma unroll
        for (int j = 0; j < 8; ++j) w.s[j] = T[ss + j][d];
        *(uint4*)(Vt + (size_t)bh * 64 * VSTRIDE + (size_t)d * VSTRIDE + s0 + ss) = w.u;
    }
}

// ---------------------------------------------------------------------------
// Flash attention v9 (verified best: 45.0us): split-K, fixed-max base-2
// softmax => partial (O,l) combine by pure addition. 27 units/bh (<=14
// chunks), grid 864 = 32 bh x 27, XCD-swizzled (4 bh/XCD, K/V L2-resident),
// units heaviest-first (LPT). 2-phase gld_lds pipeline, vmcnt(4), XOR swizzle.
// ---------------------------------------------------------------------------
#define FIXED_M2 34.6246561f    // 24 * log2(e)

// per-bh unit tables, execution-ordered by descending chunk count (LPT).
__device__ const int UTQ[27] = {6,7,8,9,10,11,12,13,13,14,14,15,15, 5,12, 4,11, 3,10, 2,9, 1,8,15, 0,7,14};
__device__ const int UK0[27] = {0,0,0,0,0,0,0,0,14,0,14,0,14, 0,14, 0,14, 0,14, 0,14, 0,14,28, 0,14,28};
__device__ const int UNC[27] = {14,14,14,14,14,14,14,14,14,14,14,14,14, 12,12, 10,10, 8,8, 6,6, 4,4,4, 2,2,2};
__device__ const int UPS[27] = {-1,0,1,2,3,4,5,6,7,8,9,10,11, -1,12, -1,13, -1,14, -1,15, -1,16,17, -1,18,19};
// reduce tables: tiles tq = 7 + ti, ti in [0,9)
__device__ const int RUN[9]    = {2,2,2,2,2,2,2,3,3};
__device__ const int RUS[9][3] = {{0,18,-1},{1,16,-1},{2,15,-1},{3,14,-1},{4,13,-1},
                                  {5,12,-1},{6,7,-1},{8,9,19},{10,11,17}};

__global__ __launch_bounds__(256) void attn_v9(const u16* __restrict__ Qh,
                                               const u16* __restrict__ Kh,
                                               const u16* __restrict__ Vt,
                                               u16* __restrict__ X,
                                               float* __restrict__ Opart,
                                               float* __restrict__ Lpart) {
    __shared__ u16 Ks[2][64 * 64];   // [buf][k-row][64 d]  (8KB/buf)
    __shared__ u16 Vs[2][64 * 64];   // [buf][d-row][64 k]  (8KB/buf)
    __shared__ u16 Ps[4][32 * 64];   // wave-private P [q][64 k], swizzled
    __shared__ float lred[4][32];
    const int tid = threadIdx.x;
    const int w = tid >> 6, lane = tid & 63;
    const int col16 = lane & 15, quad = lane >> 4;
    // XCD-aware block swizzle: 864 = 8 XCD x 108; each XCD owns 4 bh.
    const int raw = blockIdx.x;
    const int bsw = (raw & 7) * 108 + (raw >> 3);
    const int bh = bsw / 27;
    const int slot = bsw - bh * 27;
    const int tq = UTQ[slot];
    const int c0 = UK0[slot];
    const int nc = UNC[slot];
    const int ps = UPS[slot];
    const int q0 = tq * 128 + w * 32;
    const u16* Qp = Qh + (size_t)bh * 2048 * 64;
    const u16* Kp = Kh + (size_t)bh * 2048 * 64;
    const u16* Vp = Vt + (size_t)bh * 64 * VSTRIDE;
    u16* Pw = Ps[w];
    const int swz = (col16 & 7) << 3;      // row-XOR for all LDS tiles (u16 units)

    // Q fragments (used as B-operand of K*Q^T -- identical lane data)
    bf16x8 qa[2][2];
#pragma unroll
    for (int t = 0; t < 2; ++t)
#pragma unroll
        for (int hf = 0; hf < 2; ++hf)
            qa[t][hf] = *(const bf16x8*)&Qp[(size_t)(q0 + t * 16 + col16) * 64 + hf * 32 + quad * 8];

    float l_acc[2] = {0.f, 0.f};
    f32x4 o[2][4];
#pragma unroll
    for (int t = 0; t < 2; ++t)
#pragma unroll
        for (int f = 0; f < 4; ++f) o[t][f] = (f32x4){0.f, 0.f, 0.f, 0.f};

    // staging decomposition: each gld_lds covers 8 rows x 128B; lane = r*8+s.
    // swizzled granule: global slot = s ^ r  (involution; read applies same XOR)
    const int sr = lane >> 3;              // row within instr (0..7)
    const int sg = ((lane & 7) ^ sr) * 8;  // pre-swizzled 16B granule (u16 units)

    // ---- prologue: stage chunk c0 into buf 0 (4 instrs/wave: 2 K + 2 V) ----
    {
        const int k0 = c0 * 64;
#pragma unroll
        for (int i = 0; i < 2; ++i) {
            int c = w * 2 + i;
            gld_lds16(Kp + (size_t)(k0 + c * 8 + sr) * 64 + sg, &Ks[0][c * 512 + lane * 8]);
        }
#pragma unroll
        for (int i = 0; i < 2; ++i) {
            int c = w * 2 + i;
            gld_lds16(Vp + (size_t)(c * 8 + sr) * VSTRIDE + k0 + sg, &Vs[0][c * 512 + lane * 8]);
        }
    }

    for (int ci = 0; ci < nc; ++ci) {
        const int cur = ci & 1;
        const u16* KsC = Ks[cur];
        const u16* VsC = Vs[cur];

        // ---- issue next chunk's stage into the other buffer ----
        if (ci + 1 < nc) {
            const int k0n = (c0 + ci + 1) * 64;
            u16* Kd = Ks[cur ^ 1];
            u16* Vd = Vs[cur ^ 1];
#pragma unroll
            for (int i = 0; i < 2; ++i) {
                int c = w * 2 + i;
                gld_lds16(Kp + (size_t)(k0n + c * 8 + sr) * 64 + sg, Kd + c * 512 + lane * 8);
            }
#pragma unroll
            for (int i = 0; i < 2; ++i) {
                int c = w * 2 + i;
                gld_lds16(Vp + (size_t)(c * 8 + sr) * VSTRIDE + k0n + sg, Vd + c * 512 + lane * 8);
            }
            // wait only for CURRENT chunk's 4 loads; next chunk's 4 stay in flight
            asm volatile("s_waitcnt vmcnt(4)" ::: "memory");
        } else {
            asm volatile("s_waitcnt vmcnt(0)" ::: "memory");
        }
        asm volatile("s_barrier" ::: "memory");

        const int k0 = (c0 + ci) * 64;

        // ---- K*Q^T -> S^T ----
        f32x4 s[2][4];
#pragma unroll
        for (int t = 0; t < 2; ++t)
#pragma unroll
            for (int kt = 0; kt < 4; ++kt) s[t][kt] = (f32x4){0.f, 0.f, 0.f, 0.f};
#pragma unroll
        for (int kt = 0; kt < 4; ++kt) {
            const u16* kb = &KsC[(kt * 16 + col16) * 64];
            bf16x8 kf0 = *(const bf16x8*)&kb[(quad * 8) ^ swz];
            bf16x8 kf1 = *(const bf16x8*)&kb[(32 + quad * 8) ^ swz];
            s[0][kt] = mfma_16x16x32(kf0, qa[0][0], s[0][kt]);
            s[0][kt] = mfma_16x16x32(kf1, qa[0][1], s[0][kt]);
            s[1][kt] = mfma_16x16x32(kf0, qa[1][0], s[1][kt]);
            s[1][kt] = mfma_16x16x32(kf1, qa[1][1], s[1][kt]);
        }

        // ---- softmax: p = 2^(s - M2), per-lane l, packed dword P writes ----
        const bool domask = (k0 + 63 > q0);
#pragma unroll
        for (int t = 0; t < 2; ++t) {
            const int qg = q0 + t * 16 + col16;
            float rs = 0.f;
#pragma unroll
            for (int kt = 0; kt < 4; ++kt) {
                float p[4];
#pragma unroll
                for (int r = 0; r < 4; ++r) {
                    float sv = s[t][kt][r];
                    if (domask && (k0 + kt * 16 + quad * 4 + r > qg)) sv = -1e30f;
                    p[r] = __builtin_amdgcn_exp2f(sv - FIXED_M2);
                    rs += p[r];
                }
                unsigned* prow = (unsigned*)&Pw[(t * 16 + col16) * 64 + ((kt * 16 + quad * 4) ^ swz)];
                prow[0] = pk2(p[0], p[1]);
                prow[1] = pk2(p[2], p[3]);
            }
            l_acc[t] += rs;
        }
        asm volatile("s_waitcnt lgkmcnt(0)" ::: "memory");  // P writes -> reads

        // ---- PV: 16 MFMAs ----
#pragma unroll
        for (int ss = 0; ss < 2; ++ss) {
            const int ko = (ss * 32 + quad * 8) ^ swz;
            bf16x8 pf0 = *(const bf16x8*)&Pw[(col16) * 64 + ko];
            bf16x8 pf1 = *(const bf16x8*)&Pw[(16 + col16) * 64 + ko];
#pragma unroll
            for (int f = 0; f < 4; ++f) {
                bf16x8 vf = *(const bf16x8*)&VsC[(f * 16 + col16) * 64 + ko];
                o[0][f] = mfma_16x16x32(pf0, vf, o[0][f]);
                o[1][f] = mfma_16x16x32(pf1, vf, o[1][f]);
            }
        }
        // all LDS reads of buf[cur] complete before next staging overwrites
        asm volatile("s_waitcnt lgkmcnt(0)" ::: "memory");
        asm volatile("s_barrier" ::: "memory");
    }

    // ---- l reduction across quads (butterfly -> every lane has row total) ----
    float lt[2];
#pragma unroll
    for (int t = 0; t < 2; ++t) {
        float l = l_acc[t];
        l += __shfl_xor(l, 16);
        l += __shfl_xor(l, 32);
        lt[t] = l;
        if (quad == 0) lred[w][t * 16 + col16] = l;
    }
    asm volatile("s_waitcnt lgkmcnt(0)" ::: "memory");

    if (ps >= 0) {
        // ---- partial epilogue: raw O (no divide) + l to workspace ----
        const int pg = bh * 20 + ps;
        float* Op = Opart + ((size_t)pg * 128 + w * 32) * 64;
#pragma unroll
        for (int t = 0; t < 2; ++t) {
#pragma unroll
            for (int r = 0; r < 4; ++r) {
                float* Crow = Op + (t * 16 + quad * 4 + r) * 64;
#pragma unroll
                for (int f = 0; f < 4; ++f)
                    Crow[f * 16 + col16] = o[t][f][r];
            }
        }
        if (quad == 0) {
            float* Lp = Lpart + (size_t)pg * 128 + w * 32;
#pragma unroll
            for (int t = 0; t < 2; ++t) Lp[t * 16 + col16] = lt[t];
        }
        return;
    }

    // ---- direct epilogue (single-unit tile): divide and write X ----
    const int b = bh >> 4, h = bh & 15;
#pragma unroll
    for (int t = 0; t < 2; ++t) {
#pragma unroll
        for (int r = 0; r < 4; ++r) {
            float inv = 1.0f / lred[w][t * 16 + quad * 4 + r];
            int srow = q0 + t * 16 + quad * 4 + r;
            u16* Xp = X + ((size_t)(b * 2048 + srow)) * 1024 + h * 64;
#pragma unroll
            for (int f = 0; f < 4; ++f)
                Xp[f * 16 + col16] = f2b(o[t][f][r] * inv);
        }
    }
}

// ---------------------------------------------------------------------------
// attn_reduce: combine 2-3 partials per (bh, tq in 7..15): X = (sum O)/(sum l)
// ---------------------------------------------------------------------------
__global__ __launch_bounds__(256) void attn_reduce(const float* __restrict__ Opart,
                                                   const float* __restrict__ Lpart,
                                                   u16* __restrict__ X) {
    const int bh = blockIdx.x;           // 0..31
    const int ti = blockIdx.y;           // 0..8 -> tq = 7+ti
    const int tq = 7 + ti;
    const int tid = threadIdx.x;
    const int b = bh >> 4, h = bh & 15;
    const int np = RUN[ti];
    const size_t g0 = (size_t)(bh * 20 + RUS[ti][0]);
    const size_t g1 = (size_t)(bh * 20 + RUS[ti][1]);
    const size_t g2 = (np > 2) ? (size_t)(bh * 20 + RUS[ti][2]) : 0;
    const float4* O0 = (const float4*)Opart + g0 * 2048;
    const float4* O1 = (const float4*)Opart + g1 * 2048;
    const float4* O2 = (const float4*)Opart + g2 * 2048;
#pragma unroll
    for (int i = 0; i < 8; ++i) {
        int e4 = i * 256 + tid;          // float4 index within 128x64 tile
        int q = e4 >> 4, d0 = (e4 & 15) * 4;
        float4 a = O0[e4];
        float4 c = O1[e4];
        a.x += c.x; a.y += c.y; a.z += c.z; a.w += c.w;
        float l = Lpart[g0 * 128 + q] + Lpart[g1 * 128 + q];
        if (np > 2) {
            float4 d = O2[e4];
            a.x += d.x; a.y += d.y; a.z += d.z; a.w += d.w;
            l += Lpart[g2 * 128 + q];
        }
        float inv = 1.0f / l;
        ushort4 ov;
        ov.x = f2b(a.x * inv); ov.y = f2b(a.y * inv);
        ov.z = f2b(a.z * inv); ov.w = f2b(a.w * inv);
        *(ushort4*)&X[((size_t)(b * 2048 + tq * 128 + q)) * 1024 + h * 64 + d0] = ov;
    }
}

// ---------------------------------------------------------------------------
// launch
// ---------------------------------------------------------------------------
extern "C" void kernel_launch(void* const* d_in, const int* in_sizes, int n_in,
                              void* d_out, int out_size, void* d_ws, size_t ws_size,
                              hipStream_t stream) {
    const float* inputs = (const float*)d_in[0];
    const int* segpos   = (const int*)d_in[1];
    const float* W_in   = (const float*)d_in[3];
    const float* W_out  = (const float*)d_in[4];
    float* out = (float*)d_out;

    u16* ws = (u16*)d_ws;
    u16* qkv   = ws;                               // 4096*3072 bf16
    u16* x     = qkv;                              // alias (qkv dead after rope_vt)
    u16* inB   = qkv + 12582912 + 512;
    u16* WtB   = inB + 4194304 + 512;              // W_in^T  [3072][1024]
    u16* WotB  = WtB + 3145728 + 512;              // W_out^T [1024][1024]
    u16* Qh    = WotB + 1048576 + 512;             // [BH][S][64]
    u16* Kh    = Qh + 4194304 + 512;
    u16* Vt    = Kh + 4194304 + 512;               // [BH][64][VSTRIDE]
    // split-K partials live in qkv[8.39M..]/inB/WtB space (dead during attn):
    // Opart: 640 slots x 128 x 64 f32 = 10,485,760 u16; Lpart: 640 x 128 f32.
    float* Opart = (float*)(ws + 8388608);
    float* Lpart = (float*)(ws + 8388608 + 10485760);

    prep<<<dim3(8192), 256, 0, stream>>>(inputs, inB, W_in, WtB, W_out, WotB);
    gemm_tn<128, false><<<dim3(24, 32), 256, 0, stream>>>(inB, WtB, qkv, 4096, 3072, 1024);
    rope_vt<<<dim3(3072), 256, 0, stream>>>(qkv, segpos, Qh, Kh, Vt);
    attn_v9<<<dim3(864), 256, 0, stream>>>(Qh, Kh, Vt, x, Opart, Lpart);
    attn_reduce<<<dim3(32, 9), 256, 0, stream>>>(Opart, Lpart, x);
    gemm_tn64<<<dim3(16, 64), 256, 0, stream>>>(x, WotB, out, 4096, 1024, 1024);
}